// Round 12
// baseline (132.851 us; speedup 1.0000x reference)
//
#include <hip/hip_runtime.h>

// BinaryHungarianMatcherV2 cost matrix. B=32,Q=1800,T=500, out 115.2MB fp32.
// R1: 83us VALU-bound. R2: rcp/fast-trans ~59us. R3: precompute ~53us.
// R4/R5: latency/occupancy levers NEUTRAL. R6: fused dispatch ~44.7 (129.2
// bench w/ R8). R8: packed fp16 ~38.4us. R9: intra-wave valid split + nt
// REGRESSED (partial-exec stores). R10/R11: LDS b128 / 8-elem amortization
// NEUTRAL -> kernel pinned ~38-40us vs 17.5us store floor.
// R12: wave-granular invalid skip on R8 config. Wave 1 (t 256..511) skips
// all math when nb<=256 (block-uniform condition -> no divergence, store
// instrs/layout unchanged). Tests issue-per-byte-under-throttle theory.

#define K_COST_CLASS 2.0f
#define K_COST_BBOX  5.0f
#define K_COST_GIOU  2.0f
#define K_ALPHA      0.25f
#define K_INVALID    1.0e9f

constexpr int B = 32;
constexpr int Q = 1800;
constexpr int T = 500;
constexpr int ROWS = 15;          // q-rows per block; 120 x 32 grid

typedef _Float16 h2 __attribute__((ext_vector_type(2)));
typedef _Float16 h8 __attribute__((ext_vector_type(8)));

union PK { h8 w; h2 h[4]; };

static __device__ __forceinline__ h2 h2min(h2 a, h2 b) { return __builtin_elementwise_min(a, b); }
static __device__ __forceinline__ h2 h2max(h2 a, h2 b) { return __builtin_elementwise_max(a, b); }
static __device__ __forceinline__ h2 h2abs(h2 a)       { return __builtin_elementwise_abs(a); }
static __device__ __forceinline__ h2 h2splat(float x)  { _Float16 v = (_Float16)x; h2 r = {v, v}; return r; }
static __device__ __forceinline__ h2 h2pack(float a, float b) { h2 r = {(_Float16)a, (_Float16)b}; return r; }
static __device__ __forceinline__ h2 h2rcp(h2 a) {
    h2 r;
    r.x = __builtin_amdgcn_rcph(a.x);
    r.y = __builtin_amdgcn_rcph(a.y);
    return r;
}

__global__ __launch_bounds__(128) void matcher_cost_kernel(
    const float* __restrict__ pred_logits,   // [B,Q,1]
    const float* __restrict__ pred_boxes,    // [B,Q,4] cxcywh
    const float* __restrict__ boxes_padded,  // [B,T,4] cxcywh
    const int*   __restrict__ num_boxes,     // [B]
    float* __restrict__ out)                 // [B,Q,T]
{
    const int b  = blockIdx.y;
    const int q0 = blockIdx.x * ROWS;
    const int tid = threadIdx.x;

    // per-row pred params in 3 x 16B chunks (each h8 = 4 h2 splats):
    // chunk0: px0 py0 px1 py1 | chunk1: pcx pcy pw ph | chunk2: parea cls - -
    __shared__ h8 Prow[ROWS][3];

    if (tid < ROWS) {
        const int bq = b * Q + q0 + tid;
        const float4 pb =
            *reinterpret_cast<const float4*>(pred_boxes + (size_t)bq * 4);
        const float pcx = pb.x, pcy = pb.y, pw = pb.z, ph = pb.w;
        const float px0 = __builtin_fmaf(-0.5f, pw, pcx);
        const float py0 = __builtin_fmaf(-0.5f, ph, pcy);
        const float px1 = __builtin_fmaf( 0.5f, pw, pcx);
        const float py1 = __builtin_fmaf( 0.5f, ph, pcy);
        const float parea = pw * ph;

        const float s = pred_logits[bq];
        const float e_na = __expf(-fabsf(s));
        const float lse  = __logf(1.f + e_na);
        const float log_p   = fminf(s, 0.f) - lse;
        const float log_1mp = fminf(-s, 0.f) - lse;
        const float r1pe = __builtin_amdgcn_rcpf(1.f + e_na);
        const float p    = (s >= 0.f) ? r1pe : e_na * r1pe;
        const float omp  = 1.f - p;
        const float cls_term = K_COST_CLASS *
            (-K_ALPHA * omp * omp * log_p + (1.f - K_ALPHA) * p * p * log_1mp);

        PK c0, c1, c2;
        c0.h[0] = h2splat(px0);  c0.h[1] = h2splat(py0);
        c0.h[2] = h2splat(px1);  c0.h[3] = h2splat(py1);
        c1.h[0] = h2splat(pcx);  c1.h[1] = h2splat(pcy);
        c1.h[2] = h2splat(pw);   c1.h[3] = h2splat(ph);
        c2.h[0] = h2splat(parea); c2.h[1] = h2splat(cls_term);
        c2.h[2] = h2splat(0.f);   c2.h[3] = h2splat(0.f);
        Prow[tid][0] = c0.w;
        Prow[tid][1] = c1.w;
        Prow[tid][2] = c2.w;
    }

    __syncthreads();

    const int t0 = tid * 4;
    if (t0 >= T) return;    // 125/128 active
    const int nb = num_boxes[b];

    float4* orow = reinterpret_cast<float4*>(out + ((size_t)b * Q + q0) * T);

    // ---- wave-granular invalid skip: wave's whole t-range >= nb ----
    // wave 0 covers t 0..255 (never skips, nb>=1); wave 1 covers 256..499.
    // Condition uses the wave's MINIMUM t0 -> uniform across the wave: no
    // divergence, and stores below are identical instrs/layout to main path.
    const int wave_t_min = (tid & ~63) * 4;
    if (wave_t_min >= nb) {
        const float4 inv = make_float4(K_INVALID, K_INVALID, K_INVALID, K_INVALID);
        for (int qi = 0; qi < ROWS; ++qi)
            orow[(size_t)qi * (T / 4) + tid] = inv;
        return;
    }

    // ---- target-side regs: 2 h2 pairs covering t0..t0+3 ----
    h2 tcx[2], tcy[2], tw_[2], th_[2];
    h2 tx0[2], ty0[2], tx1[2], ty1[2], tarea[2];
    bool valid[4];
    {
        const float4* tb_base =
            reinterpret_cast<const float4*>(boxes_padded + ((size_t)b * T + t0) * 4);
#pragma unroll
        for (int k = 0; k < 2; ++k) {
            const float4 ta = tb_base[2 * k];
            const float4 tb = tb_base[2 * k + 1];
            tcx[k] = h2pack(ta.x, tb.x);
            tcy[k] = h2pack(ta.y, tb.y);
            tw_[k] = h2pack(ta.z, tb.z);
            th_[k] = h2pack(ta.w, tb.w);
            tx0[k] = h2pack(__builtin_fmaf(-0.5f, ta.z, ta.x),
                            __builtin_fmaf(-0.5f, tb.z, tb.x));
            ty0[k] = h2pack(__builtin_fmaf(-0.5f, ta.w, ta.y),
                            __builtin_fmaf(-0.5f, tb.w, tb.y));
            tx1[k] = h2pack(__builtin_fmaf( 0.5f, ta.z, ta.x),
                            __builtin_fmaf( 0.5f, tb.z, tb.x));
            ty1[k] = h2pack(__builtin_fmaf( 0.5f, ta.w, ta.y),
                            __builtin_fmaf( 0.5f, tb.w, tb.y));
            tarea[k] = h2pack(ta.z * ta.w, tb.z * tb.w);
        }
#pragma unroll
        for (int j = 0; j < 4; ++j) valid[j] = (t0 + j) < nb;
    }

    const h2 zero2 = h2splat(0.f);
    const h2 dmin2 = h2splat(0.00390625f);   // 2^-8 denom clamp
    const h2 five2 = h2splat(K_COST_BBOX);
    const h2 ntwo2 = h2splat(-K_COST_GIOU);

    for (int qi = 0; qi < ROWS; ++qi) {
        PK c0, c1, c2;
        c0.w = Prow[qi][0];     // ds_read_b128
        c1.w = Prow[qi][1];
        c2.w = Prow[qi][2];
        const h2 px0 = c0.h[0], py0 = c0.h[1], px1 = c0.h[2], py1 = c0.h[3];
        const h2 pcx = c1.h[0], pcy = c1.h[1], pw = c1.h[2], ph = c1.h[3];
        const h2 parea = c2.h[0], cls2 = c2.h[1];

        float rf[4];
#pragma unroll
        for (int k = 0; k < 2; ++k) {
            // L1 cost (packed): sum of |diffs|
            const h2 cb2 = (h2abs(pcx - tcx[k]) + h2abs(pcy - tcy[k]))
                         + (h2abs(pw - tw_[k]) + h2abs(ph - th_[k]));

            // intersection extents (pre-clamp)
            const h2 iwp = h2min(px1, tx1[k]) - h2max(px0, tx0[k]);
            const h2 ihp = h2min(py1, ty1[k]) - h2max(py0, ty0[k]);
            const h2 inter = h2max(iwp, zero2) * h2max(ihp, zero2);
            const h2 uni   = (parea + tarea[k]) - inter;

            // enclosing box via max+min=sum identity
            const h2 ew = (pw + tw_[k]) - iwp;
            const h2 eh = (ph + th_[k]) - ihp;
            const h2 earea = ew * eh;

            // fused giou = (earea*(inter-uni) + uni^2) / (uni*earea)
            const h2 denom = h2max(uni * earea, dmin2);
            const h2 rden  = h2rcp(denom);
            const h2 num   = earea * (inter - uni) + uni * uni;
            const h2 giou  = num * rden;

            // c = 5*cb + cls - 2*giou
            const h2 c2v = five2 * cb2 + (ntwo2 * giou + cls2);

            rf[2 * k]     = valid[2 * k]     ? (float)c2v.x : K_INVALID;
            rf[2 * k + 1] = valid[2 * k + 1] ? (float)c2v.y : K_INVALID;
        }
        orow[(size_t)qi * (T / 4) + tid] = make_float4(rf[0], rf[1], rf[2], rf[3]);
    }
}

extern "C" void kernel_launch(void* const* d_in, const int* in_sizes, int n_in,
                              void* d_out, int out_size, void* d_ws, size_t ws_size,
                              hipStream_t stream) {
    const float* pred_logits  = (const float*)d_in[0];
    const float* pred_boxes   = (const float*)d_in[1];
    const float* boxes_padded = (const float*)d_in[2];
    const int*   num_boxes    = (const int*)d_in[3];
    float* out = (float*)d_out;

    dim3 grid(Q / ROWS, B);      // 120 x 32 = 3840 blocks
    matcher_cost_kernel<<<grid, dim3(128), 0, stream>>>(
        pred_logits, pred_boxes, boxes_padded, num_boxes, out);
}

// Round 13
// 129.172 us; speedup vs baseline: 1.0285x; 1.0285x over previous
//
#include <hip/hip_runtime.h>

// BinaryHungarianMatcherV2 cost matrix. B=32,Q=1800,T=500, out 115.2MB fp32.
// Final config = R8 (best measured: 129.2us bench).
// History: R1 block/(b,q) 83us VALU-bound 94% -> R2 rcp/fast-trans ~59 ->
// R3 precompute+q-loop ~53 -> R6 single fused dispatch ~44.7 -> R8 packed
// fp16 (v_pk_*_f16, 2 targets/slot) 129.2us bench.
// Neutral/dead levers (R4,R5,R10,R11,R12): occupancy 18->30 waves/CU,
// s_load prefetch, nt stores, LDS b128 packing, 8-elem amortization,
// wave-granular invalid skip (-25% math issue) -- ALL within noise.
// R9 regression: intra-wave valid split -> partial-exec stores.
// Conclusion: timed iteration is HBM-write-drain bound at harness level
// (poison-fill 460.8MB + kernel 115.2MB = 576MB @ 6.5TB/s ~ 88.6us shared
// write-port floor + launch/validation gaps). Kernel compute is below the
// drain floor; mandatory 115.2MB output pins the rest. Roofline.

#define K_COST_CLASS 2.0f
#define K_COST_BBOX  5.0f
#define K_COST_GIOU  2.0f
#define K_ALPHA      0.25f
#define K_INVALID    1.0e9f

constexpr int B = 32;
constexpr int Q = 1800;
constexpr int T = 500;
constexpr int ROWS = 15;          // q-rows per block; 120 x 32 grid

typedef _Float16 h2 __attribute__((ext_vector_type(2)));

static __device__ __forceinline__ h2 h2min(h2 a, h2 b) { return __builtin_elementwise_min(a, b); }
static __device__ __forceinline__ h2 h2max(h2 a, h2 b) { return __builtin_elementwise_max(a, b); }
static __device__ __forceinline__ h2 h2abs(h2 a)       { return __builtin_elementwise_abs(a); }
static __device__ __forceinline__ h2 h2splat(float x)  { _Float16 v = (_Float16)x; h2 r = {v, v}; return r; }
static __device__ __forceinline__ h2 h2pack(float a, float b) { h2 r = {(_Float16)a, (_Float16)b}; return r; }
static __device__ __forceinline__ h2 h2rcp(h2 a) {
    h2 r;
    r.x = __builtin_amdgcn_rcph(a.x);
    r.y = __builtin_amdgcn_rcph(a.y);
    return r;
}

__global__ __launch_bounds__(128) void matcher_cost_kernel(
    const float* __restrict__ pred_logits,   // [B,Q,1]
    const float* __restrict__ pred_boxes,    // [B,Q,4] cxcywh
    const float* __restrict__ boxes_padded,  // [B,T,4] cxcywh
    const int*   __restrict__ num_boxes,     // [B]
    float* __restrict__ out)                 // [B,Q,T]
{
    const int b  = blockIdx.y;
    const int q0 = blockIdx.x * ROWS;
    const int tid = threadIdx.x;

    // per-row pred params, pre-splatted h2 (both halves equal):
    // [0]=px0 [1]=py0 [2]=px1 [3]=py1 [4]=pcx [5]=pcy [6]=pw [7]=ph
    // [8]=parea [9]=cls_term (pad to 12)
    __shared__ h2 Prow[ROWS][12];

    if (tid < ROWS) {
        const int bq = b * Q + q0 + tid;
        const float4 pb =
            *reinterpret_cast<const float4*>(pred_boxes + (size_t)bq * 4);
        const float pcx = pb.x, pcy = pb.y, pw = pb.z, ph = pb.w;
        const float px0 = __builtin_fmaf(-0.5f, pw, pcx);
        const float py0 = __builtin_fmaf(-0.5f, ph, pcy);
        const float px1 = __builtin_fmaf( 0.5f, pw, pcx);
        const float py1 = __builtin_fmaf( 0.5f, ph, pcy);
        const float parea = pw * ph;

        const float s = pred_logits[bq];
        const float e_na = __expf(-fabsf(s));
        const float lse  = __logf(1.f + e_na);
        const float log_p   = fminf(s, 0.f) - lse;
        const float log_1mp = fminf(-s, 0.f) - lse;
        const float r1pe = __builtin_amdgcn_rcpf(1.f + e_na);
        const float p    = (s >= 0.f) ? r1pe : e_na * r1pe;
        const float omp  = 1.f - p;
        const float cls_term = K_COST_CLASS *
            (-K_ALPHA * omp * omp * log_p + (1.f - K_ALPHA) * p * p * log_1mp);

        Prow[tid][0] = h2splat(px0);
        Prow[tid][1] = h2splat(py0);
        Prow[tid][2] = h2splat(px1);
        Prow[tid][3] = h2splat(py1);
        Prow[tid][4] = h2splat(pcx);
        Prow[tid][5] = h2splat(pcy);
        Prow[tid][6] = h2splat(pw);
        Prow[tid][7] = h2splat(ph);
        Prow[tid][8] = h2splat(parea);
        Prow[tid][9] = h2splat(cls_term);
    }

    const int t0 = tid * 4;
    const int nb = num_boxes[b];

    // ---- target-side regs: 2 h2 pairs covering t0..t0+3 ----
    h2 tcx[2], tcy[2], tw_[2], th_[2];
    h2 tx0[2], ty0[2], tx1[2], ty1[2], tarea[2];
    bool valid[4];
    if (t0 < T) {
        const float4* tb_base =
            reinterpret_cast<const float4*>(boxes_padded + ((size_t)b * T + t0) * 4);
#pragma unroll
        for (int k = 0; k < 2; ++k) {
            const float4 ta = tb_base[2 * k];
            const float4 tb = tb_base[2 * k + 1];
            tcx[k] = h2pack(ta.x, tb.x);
            tcy[k] = h2pack(ta.y, tb.y);
            tw_[k] = h2pack(ta.z, tb.z);
            th_[k] = h2pack(ta.w, tb.w);
            tx0[k] = h2pack(__builtin_fmaf(-0.5f, ta.z, ta.x),
                            __builtin_fmaf(-0.5f, tb.z, tb.x));
            ty0[k] = h2pack(__builtin_fmaf(-0.5f, ta.w, ta.y),
                            __builtin_fmaf(-0.5f, tb.w, tb.y));
            tx1[k] = h2pack(__builtin_fmaf( 0.5f, ta.z, ta.x),
                            __builtin_fmaf( 0.5f, tb.z, tb.x));
            ty1[k] = h2pack(__builtin_fmaf( 0.5f, ta.w, ta.y),
                            __builtin_fmaf( 0.5f, tb.w, tb.y));
            tarea[k] = h2pack(ta.z * ta.w, tb.z * tb.w);
        }
#pragma unroll
        for (int j = 0; j < 4; ++j) valid[j] = (t0 + j) < nb;
    }

    __syncthreads();
    if (t0 >= T) return;    // 125/128 active

    float4* orow = reinterpret_cast<float4*>(out + ((size_t)b * Q + q0) * T);

    const h2 zero2 = h2splat(0.f);
    const h2 dmin2 = h2splat(0.00390625f);   // 2^-8 denom clamp
    const h2 five2 = h2splat(K_COST_BBOX);
    const h2 ntwo2 = h2splat(-K_COST_GIOU);

    for (int qi = 0; qi < ROWS; ++qi) {
        const h2 px0 = Prow[qi][0], py0 = Prow[qi][1];
        const h2 px1 = Prow[qi][2], py1 = Prow[qi][3];
        const h2 pcx = Prow[qi][4], pcy = Prow[qi][5];
        const h2 pw  = Prow[qi][6], ph  = Prow[qi][7];
        const h2 parea = Prow[qi][8], cls2 = Prow[qi][9];

        float rf[4];
#pragma unroll
        for (int k = 0; k < 2; ++k) {
            // L1 cost (packed): sum of |diffs|
            const h2 cb2 = (h2abs(pcx - tcx[k]) + h2abs(pcy - tcy[k]))
                         + (h2abs(pw - tw_[k]) + h2abs(ph - th_[k]));

            // intersection extents (pre-clamp)
            const h2 iwp = h2min(px1, tx1[k]) - h2max(px0, tx0[k]);
            const h2 ihp = h2min(py1, ty1[k]) - h2max(py0, ty0[k]);
            const h2 inter = h2max(iwp, zero2) * h2max(ihp, zero2);
            const h2 uni   = (parea + tarea[k]) - inter;

            // enclosing box via max+min=sum identity
            const h2 ew = (pw + tw_[k]) - iwp;
            const h2 eh = (ph + th_[k]) - ihp;
            const h2 earea = ew * eh;

            // fused giou = (earea*(inter-uni) + uni^2) / (uni*earea)
            const h2 denom = h2max(uni * earea, dmin2);
            const h2 rden  = h2rcp(denom);
            const h2 num   = earea * (inter - uni) + uni * uni;
            const h2 giou  = num * rden;

            // c = 5*cb + cls - 2*giou
            const h2 c2 = five2 * cb2 + (ntwo2 * giou + cls2);

            rf[2 * k]     = valid[2 * k]     ? (float)c2.x : K_INVALID;
            rf[2 * k + 1] = valid[2 * k + 1] ? (float)c2.y : K_INVALID;
        }
        orow[(size_t)qi * (T / 4) + tid] = make_float4(rf[0], rf[1], rf[2], rf[3]);
    }
}

extern "C" void kernel_launch(void* const* d_in, const int* in_sizes, int n_in,
                              void* d_out, int out_size, void* d_ws, size_t ws_size,
                              hipStream_t stream) {
    const float* pred_logits  = (const float*)d_in[0];
    const float* pred_boxes   = (const float*)d_in[1];
    const float* boxes_padded = (const float*)d_in[2];
    const int*   num_boxes    = (const int*)d_in[3];
    float* out = (float*)d_out;

    dim3 grid(Q / ROWS, B);      // 120 x 32 = 3840 blocks
    matcher_cost_kernel<<<grid, dim3(128), 0, stream>>>(
        pred_logits, pred_boxes, boxes_padded, num_boxes, out);
}